// Round 3
// baseline (577.544 us; speedup 1.0000x reference)
//
#include <hip/hip_runtime.h>

#define NN 1024
#define DD 128
#define NBLK 1024

typedef __attribute__((ext_vector_type(8))) __bf16 bf16x8;
typedef __attribute__((ext_vector_type(4))) float f32x4;

__device__ __forceinline__ float us2f(unsigned short b) { return __uint_as_float(((unsigned)b) << 16); }
__device__ __forceinline__ unsigned short f2bf(float f) {
    unsigned x = __float_as_uint(f);
    return (unsigned short)((x + 0x7fffu + ((x >> 16) & 1u)) >> 16);   // RNE
}

// Grid barrier (1024 blocks): 16 sub-counters (128B lines, 64 blocks each) -> master -> flag.
// Relaxed polling on one line (no per-iteration invalidate); one acquire fence on exit.
// Co-residency: 34.4KB LDS -> 4 blocks/CU, launch_bounds caps VGPR at 128 -> 4 waves/SIMD;
// 1024 = 256 CUs x 4 blocks, all resident => spin is safe.
__device__ __forceinline__ void gridbar(unsigned* bar, unsigned ep) {
    __syncthreads();
    if (threadIdx.x == 0) {
        __threadfence();   // release: drain this block's stores to the coherence point
        unsigned old = __hip_atomic_fetch_add(&bar[(blockIdx.x & 15) << 5], 1u,
                                              __ATOMIC_RELAXED, __HIP_MEMORY_SCOPE_AGENT);
        if (old == (ep << 6) - 1) {                    // 64 blocks/sub-counter done
            unsigned mold = __hip_atomic_fetch_add(&bar[512], 1u,
                                                   __ATOMIC_RELAXED, __HIP_MEMORY_SCOPE_AGENT);
            if (mold == (ep << 4) - 1)                 // all 16 sub-counters done
                __hip_atomic_store(&bar[544], ep, __ATOMIC_RELAXED, __HIP_MEMORY_SCOPE_AGENT);
        }
        while (__hip_atomic_load(&bar[544], __ATOMIC_RELAXED, __HIP_MEMORY_SCOPE_AGENT) < ep)
            __builtin_amdgcn_s_sleep(4);
        __threadfence();   // acquire: invalidate stale cached lines
    }
    __syncthreads();
}

// column-GEMM: out[d] = sum_k W[k*DD+d] * x[k]; x in LDS (broadcast), W coalesced via L2.
// 4 independent accumulators for memory-level parallelism.
__device__ __forceinline__ float colgemm(const float* __restrict__ W, const float* x, int d) {
    float a0 = 0.f, a1 = 0.f, a2 = 0.f, a3 = 0.f;
#pragma unroll 8
    for (int k = 0; k < DD; k += 4) {
        a0 = fmaf(W[(k + 0) * DD + d], x[k + 0], a0);
        a1 = fmaf(W[(k + 1) * DD + d], x[k + 1], a1);
        a2 = fmaf(W[(k + 2) * DD + d], x[k + 2], a2);
        a3 = fmaf(W[(k + 3) * DD + d], x[k + 3], a3);
    }
    return (a0 + a1) + (a2 + a3);
}

__global__ __launch_bounds__(256, 4) void k_fused(
    const float* __restrict__ adj, const float* __restrict__ ew,
    const float* __restrict__ nf, const float* __restrict__ We, const float* __restrict__ be,
    const float* __restrict__ Wu, const float* __restrict__ bu,
    const float* __restrict__ Wv, const float* __restrict__ bv,
    const float* __restrict__ Wg, const float* __restrict__ bg,
    const float* __restrict__ Wc1, const float* __restrict__ bc1,
    const float* __restrict__ Wc2, const float* __restrict__ bc2,
    float* __restrict__ h, float* __restrict__ u,
    unsigned short* __restrict__ vTh, unsigned short* __restrict__ vTl,
    float* __restrict__ P,
    unsigned short* __restrict__ adjH, unsigned short* __restrict__ adjL,
    float* __restrict__ hi, float* __restrict__ hj,
    float* __restrict__ S1, float* __restrict__ S2,
    float* __restrict__ lossAcc, unsigned* __restrict__ counter,
    unsigned* __restrict__ barCnt, float* __restrict__ outL)
{
    __shared__ union SMem {
        struct { float aS[DD], uS[DD], hS[DD], gacc[2][DD], wred[4]; } g;  // embed/gate
        struct { float hiT[32][132], hjT[32][132], wS[DD], wred[4]; } e;   // edge (~34.4KB)
    } sm;

    int tid = threadIdx.x;
    int bx = blockIdx.x;
    int d = tid & 127, half = tid >> 7;
    int lane = tid & 63, wid = tid >> 6;
    unsigned ep = 0;

    // ---------------- Phase 0a: adj -> bf16 hi/lo split (1 float4 per thread, exact cover)
    {
        int i = bx * 256 + tid;             // 262144 threads == NN*NN/4 float4s
        int idx = i * 4;
        float4 a = *(const float4*)(adj + idx);
        ushort4 hv, lv;
        hv.x = f2bf(a.x); lv.x = f2bf(a.x - us2f(hv.x));
        hv.y = f2bf(a.y); lv.y = f2bf(a.y - us2f(hv.y));
        hv.z = f2bf(a.z); lv.z = f2bf(a.z - us2f(hv.z));
        hv.w = f2bf(a.w); lv.w = f2bf(a.w - us2f(hv.w));
        *(ushort4*)(adjH + idx) = hv;
        *(ushort4*)(adjL + idx) = lv;
    }
    // ---------------- Phase 0b: embed (1 row per block) + layer-0 u/v GEMM
    {
        int row = bx;
        if (tid < 128) {
            float a = be[tid];
#pragma unroll
            for (int k = 0; k < 3; ++k) a = fmaf(nf[row * 3 + k], We[k * DD + tid], a);
            h[row * DD + tid] = a;
            sm.g.hS[tid] = a;
        }
        __syncthreads();
        float av = colgemm(half ? Wv : Wu, sm.g.hS, d);
        if (half == 0) {
            u[row * DD + d] = av + bu[d];
        } else {
            float v = av + bv[d];
            unsigned short hvv = f2bf(v);
            vTh[(size_t)d * NN + row] = hvv;
            vTl[(size_t)d * NN + row] = f2bf(v - us2f(hvv));
        }
    }
    gridbar(barCnt, ++ep);

    // ---------------- 3 GCN layers
    for (int l = 0; l < 3; ++l) {
        // ---- agg partials: P[kc] = adjH/L[:, kc-chunk] @ v[kc-chunk, :] (1 task per block)
        {
            int t = bx;
            int nt = t >> 7;                 // 0..7
            int mt = (t >> 1) & 63;          // 0..63
            int kc = ((t & 1) << 2) | wid;   // 0..7
            int m = lane & 15, quad = lane >> 4;
            int k0 = kc * 128 + quad * 8;
            const unsigned short* ah = adjH + (size_t)(mt * 16 + m) * NN + k0;
            const unsigned short* al = adjL + (size_t)(mt * 16 + m) * NN + k0;
            const unsigned short* bh = vTh + (size_t)(nt * 16 + m) * NN + k0;
            const unsigned short* bl = vTl + (size_t)(nt * 16 + m) * NN + k0;
            f32x4 acc = {0.f, 0.f, 0.f, 0.f};
#pragma unroll
            for (int kt = 0; kt < 4; ++kt) {
                bf16x8 aH = *(const bf16x8*)(ah + kt * 32);
                bf16x8 aL = *(const bf16x8*)(al + kt * 32);
                bf16x8 bH = *(const bf16x8*)(bh + kt * 32);
                bf16x8 bL = *(const bf16x8*)(bl + kt * 32);
                acc = __builtin_amdgcn_mfma_f32_16x16x32_bf16(aH, bH, acc, 0, 0, 0);
                acc = __builtin_amdgcn_mfma_f32_16x16x32_bf16(aH, bL, acc, 0, 0, 0);
                acc = __builtin_amdgcn_mfma_f32_16x16x32_bf16(aL, bH, acc, 0, 0, 0);
            }
            float* Pk = P + (size_t)kc * (NN * DD);
            int row0 = mt * 16 + quad * 4;
            int col = nt * 16 + m;
#pragma unroll
            for (int r = 0; r < 4; ++r) Pk[(row0 + r) * DD + col] = acc[r];
        }
        gridbar(barCnt, ++ep);

        // ---- gate + h-update + next-stage GEMM (1 row per block)
        {
            int row = bx;
            if (tid < 128) {
                float s = 0.f;
#pragma unroll
                for (int c = 0; c < 8; ++c) s += P[(size_t)c * (NN * DD) + row * DD + tid];
                sm.g.aS[tid] = s;
            } else {
                sm.g.uS[tid - 128] = u[row * DD + (tid - 128)];
            }
            __syncthreads();
            const float* WA = Wg + l * 32768;
            const float* WB = WA + DD * DD;
            sm.g.gacc[half][d] = colgemm(half ? WB : WA, half ? sm.g.aS : sm.g.uS, d);
            __syncthreads();
            if (tid < 128) {
                float g = 1.f / (1.f + __expf(-(sm.g.gacc[0][d] + sm.g.gacc[1][d] + bg[l * 128 + d])));
                float nh = fmaf(g, sm.g.aS[d], h[row * DD + d]);
                nh = nh > 0.f ? nh : 0.f;
                if (l < 2) h[row * DD + d] = nh;
                sm.g.hS[d] = nh;
            }
            __syncthreads();
            const float* W2 = (l < 2) ? ((half ? Wv : Wu) + (l + 1) * 16384)
                                      : (Wc1 + (half ? DD * DD : 0));
            float av = colgemm(W2, sm.g.hS, d);
            if (l < 2) {
                if (half == 0) {
                    u[row * DD + d] = av + bu[(l + 1) * 128 + d];
                } else {
                    float v = av + bv[(l + 1) * 128 + d];
                    unsigned short hvv = f2bf(v);
                    vTh[(size_t)d * NN + row] = hvv;
                    vTl[(size_t)d * NN + row] = f2bf(v - us2f(hvv));
                }
            } else {
                float val = av + (half ? 0.f : bc1[d]);
                (half ? hj : hi)[row * DD + d] = val;
                float p = val * Wc2[d];
#pragma unroll
                for (int off = 32; off; off >>= 1) p += __shfl_down(p, off);
                if (lane == 0) sm.g.wred[wid] = p;
                __syncthreads();
                if (tid == 0) S1[row] = sm.g.wred[0] + sm.g.wred[1];
                if (tid == 128) S2[row] = sm.g.wred[2] + sm.g.wred[3];
            }
        }
        gridbar(barCnt, ++ep);
    }

    // ---------------- edge classifier: 32x32 logits tile per block + loss partial.
    // LDS layouts [32][132]: 132 % 32 == 4 => all read/write patterns bank-conflict-free.
    {
        int i0 = (bx >> 5) * 32, j0 = (bx & 31) * 32;
        if (tid < 128) sm.e.wS[tid] = Wc2[tid];
        for (int e2 = tid; e2 < 32 * 128; e2 += 256) {
            int r = e2 >> 7, hh = e2 & 127;
            sm.e.hiT[r][hh] = hi[(i0 + r) * DD + hh];
            sm.e.hjT[r][hh] = hj[(j0 + r) * DD + hh];
        }
        __syncthreads();
        int tx = tid & 7, ty = tid >> 3;       // 8 x 32 threads -> 4 cols x 1 row each
        float4 acc = {0.f, 0.f, 0.f, 0.f};
#pragma unroll 4
        for (int hh = 0; hh < 128; hh += 4) {
            f32x4 a4 = *(const f32x4*)&sm.e.hiT[ty][hh];
            f32x4 w4 = *(const f32x4*)&sm.e.wS[hh];
#pragma unroll
            for (int q = 0; q < 4; ++q) {
                f32x4 b4 = *(const f32x4*)&sm.e.hjT[tx * 4 + q][hh];
                float aq = (&acc.x)[q];
                aq = fmaf(fabsf(a4[0] + b4[0]), w4[0], aq);
                aq = fmaf(fabsf(a4[1] + b4[1]), w4[1], aq);
                aq = fmaf(fabsf(a4[2] + b4[2]), w4[2], aq);
                aq = fmaf(fabsf(a4[3] + b4[3]), w4[3], aq);
                (&acc.x)[q] = aq;
            }
        }
        float bcv = bc2[0];
        int i = i0 + ty;
        int jb = j0 + tx * 4;
        float s1 = S1[i];
        f32x4 s2 = *(const f32x4*)(S2 + jb);
        f32x4 lg;
#pragma unroll
        for (int q = 0; q < 4; ++q)
            lg[q] = fmaf(0.5f, (&acc.x)[q] + s1 + s2[q], bcv);
        *(f32x4*)(outL + (size_t)i * NN + jb) = lg;
        f32x4 a4 = *(const f32x4*)(adj + (size_t)i * NN + jb);
        f32x4 e4 = *(const f32x4*)(ew + (size_t)i * NN + jb);
        float ls = 0.f;
#pragma unroll
        for (int q = 0; q < 4; ++q) {
            float t = fmaf(lg[q], a4[q], -e4[q]);
            ls = fmaf(t, t, ls);
        }
#pragma unroll
        for (int off = 32; off; off >>= 1) ls += __shfl_down(ls, off);
        if (lane == 0) sm.e.wred[wid] = ls;
        __syncthreads();
        if (tid == 0) {
            float bls = (sm.e.wred[0] + sm.e.wred[1]) + (sm.e.wred[2] + sm.e.wred[3]);
            atomicAdd(lossAcc, bls);
            __threadfence();
            unsigned old = atomicAdd(counter, 1u);
            if (old == NBLK - 1u) {
                __threadfence();
                outL[(size_t)NN * NN] = (*(volatile float*)lossAcc) * (1.f / (1024.f * 1024.f));
            }
        }
    }
}

extern "C" void kernel_launch(void* const* d_in, const int* in_sizes, int n_in,
                              void* d_out, int out_size, void* d_ws, size_t ws_size,
                              hipStream_t stream)
{
    const float* nf  = (const float*)d_in[0];
    const float* adj = (const float*)d_in[1];
    const float* ew  = (const float*)d_in[2];
    const float* We  = (const float*)d_in[3];
    const float* be  = (const float*)d_in[4];
    const float* Wu  = (const float*)d_in[5];
    const float* bu  = (const float*)d_in[6];
    const float* Wv  = (const float*)d_in[7];
    const float* bv  = (const float*)d_in[8];
    const float* Wg  = (const float*)d_in[9];
    const float* bg  = (const float*)d_in[10];
    const float* Wc1 = (const float*)d_in[11];
    const float* bc1 = (const float*)d_in[12];
    const float* Wc2 = (const float*)d_in[13];
    const float* bc2 = (const float*)d_in[14];

    float* ws = (float*)d_ws;
    float* h   = ws;                                          // 131072
    float* u   = ws + 131072;                                 // 131072
    unsigned short* vTh = (unsigned short*)(ws + 262144);     // 131072 bf16
    unsigned short* vTl = (unsigned short*)(ws + 327680);     // 131072 bf16
    float* P   = ws + 393216;                                 // 8 x 131072
    unsigned short* adjH = (unsigned short*)(ws + 1441792);   // 1M bf16
    unsigned short* adjL = (unsigned short*)(ws + 1966080);   // 1M bf16
    float* hi  = ws + 2490368;                                // 131072
    float* hj  = ws + 2621440;                                // 131072
    float* S1  = ws + 2752512;                                // 1024
    float* S2  = ws + 2753536;                                // 1024
    float* lossAcc = ws + 2754560;                            // 1
    unsigned* counter = (unsigned*)(ws + 2754561);            // 1
    unsigned* barCnt = (unsigned*)(ws + 2754592);             // 545 uints (sub/master/flag)

    // zero lossAcc + finalize counter + barrier state (capture-legal)
    hipMemsetAsync((void*)lossAcc, 0, 2560, stream);
    k_fused<<<NBLK, 256, 0, stream>>>(adj, ew, nf, We, be, Wu, bu, Wv, bv, Wg, bg,
                                      Wc1, bc1, Wc2, bc2, h, u, vTh, vTl, P,
                                      adjH, adjL, hi, hj, S1, S2,
                                      lossAcc, counter, barCnt, (float*)d_out);
}

// Round 4
// 215.417 us; speedup vs baseline: 2.6810x; 2.6810x over previous
//
#include <hip/hip_runtime.h>

#define NN 1024
#define DD 128
#define NBLK 256

typedef __attribute__((ext_vector_type(4))) float f32x4;

// Grid barrier (256 blocks): 16 sub-counters (128B lines, 16 blocks each) -> master -> flag.
// tid0-only fences; RELAXED polling on one line (no per-poll invalidate); one acquire
// fence on exit. 256 blocks x 1024 threads = 1 block/CU (55KB LDS, VGPR<=128): all resident.
__device__ __forceinline__ void gridbar(unsigned* bar, unsigned ep) {
    __syncthreads();
    if (threadIdx.x == 0) {
        __threadfence();   // release: drain this block's stores toward IC
        unsigned old = __hip_atomic_fetch_add(&bar[(blockIdx.x & 15) << 5], 1u,
                                              __ATOMIC_RELAXED, __HIP_MEMORY_SCOPE_AGENT);
        if (old == (ep << 4) - 1) {                    // 16 blocks/sub-counter done
            unsigned mold = __hip_atomic_fetch_add(&bar[512], 1u,
                                                   __ATOMIC_RELAXED, __HIP_MEMORY_SCOPE_AGENT);
            if (mold == (ep << 4) - 1)                 // all 16 sub-counters done
                __hip_atomic_store(&bar[544], ep, __ATOMIC_RELAXED, __HIP_MEMORY_SCOPE_AGENT);
        }
        while (__hip_atomic_load(&bar[544], __ATOMIC_RELAXED, __HIP_MEMORY_SCOPE_AGENT) < ep)
            __builtin_amdgcn_s_sleep(4);
        __threadfence();   // acquire: invalidate stale cached lines once
    }
    __syncthreads();
}

// out[d] = sum_k W[k*DD+d] * x[k]; x in LDS (broadcast b128), W coalesced across d-lanes.
__device__ __forceinline__ float dotW(const float* __restrict__ W, const float* x, int d) {
    float a0 = 0.f, a1 = 0.f, a2 = 0.f, a3 = 0.f;
#pragma unroll 8
    for (int k = 0; k < DD; k += 4) {
        f32x4 x4 = *(const f32x4*)(x + k);
        a0 = fmaf(W[(k + 0) * DD + d], x4[0], a0);
        a1 = fmaf(W[(k + 1) * DD + d], x4[1], a1);
        a2 = fmaf(W[(k + 2) * DD + d], x4[2], a2);
        a3 = fmaf(W[(k + 3) * DD + d], x4[3], a3);
    }
    return (a0 + a1) + (a2 + a3);
}

__global__ __launch_bounds__(1024, 4) void k_fused(
    const float* __restrict__ adj, const float* __restrict__ ew,
    const float* __restrict__ nf, const float* __restrict__ We, const float* __restrict__ be,
    const float* __restrict__ Wu, const float* __restrict__ bu,
    const float* __restrict__ Wv, const float* __restrict__ bv,
    const float* __restrict__ Wg, const float* __restrict__ bg,
    const float* __restrict__ Wc1, const float* __restrict__ bc1,
    const float* __restrict__ Wc2, const float* __restrict__ bc2,
    float* __restrict__ v0, float* __restrict__ v1,
    float* __restrict__ hi, float* __restrict__ hj,
    float* __restrict__ S1, float* __restrict__ S2,
    float* __restrict__ lossAcc, unsigned* __restrict__ counter,
    unsigned* __restrict__ barCnt, float* __restrict__ outL)
{
    __shared__ float hS[4][DD], uS[4][DD], wS[DD];          // persistent per-block state
    __shared__ union {
        struct {
            float adjS[4][NN];        // 16KB: own adj rows, staged once, live through layers
            float pS[8][4][DD];       // 16KB: k-chunk partials
            float aggS[4][DD];        // 2KB
            float gacc[2][4][DD];     // 4KB
            float sred[2][4][2];
        } g;
        struct {
            float hiS[64][132];       // 33.8KB (pad 132: i-rows spread 4 banks)
            float hjS[32][134];       // 16.8KB (pad 134: 2-way only => free)
            float lred[16];
        } e;
    } sm;

    int tid = threadIdx.x, bx = blockIdx.x;
    int row0 = bx * 4;
    unsigned ep = 0;

    // ---------------- Phase 0: stage adj rows + embed + layer-0 u/v ----------------
    {
        int r = tid >> 8, k0 = (tid & 255) << 2;
        *(f32x4*)&sm.g.adjS[r][k0] = *(const f32x4*)(adj + (size_t)(row0 + r) * NN + k0);
    }
    if (tid < 512) {
        int r = tid >> 7, d = tid & 127;
        float a = be[d];
#pragma unroll
        for (int k = 0; k < 3; ++k) a = fmaf(nf[(row0 + r) * 3 + k], We[k * DD + d], a);
        hS[r][d] = a;
    }
    __syncthreads();
    {
        int half = tid >> 9, r = (tid >> 7) & 3, d = tid & 127;
        float av = dotW(half ? Wv : Wu, hS[r], d);
        if (!half) uS[r][d] = av + bu[d];
        else       v0[(size_t)(row0 + r) * DD + d] = av + bv[d];
    }
    gridbar(barCnt, ++ep);

    // ---------------- 3 GCN layers: one barrier each ----------------
    for (int l = 0; l < 3; ++l) {
        const float* vin = (l & 1) ? v1 : v0;
        float* vout = (l & 1) ? v0 : v1;

        // agg[r][d] = sum_k adj[row0+r][k] * vin[k][d]  (full K, k-chunked over 8 groups)
        {
            int kk = tid >> 7, d = tid & 127;
            int kb = kk << 7;
            float ac0 = 0.f, ac1 = 0.f, ac2 = 0.f, ac3 = 0.f;
#pragma unroll 2
            for (int k = 0; k < 128; k += 4) {
                f32x4 a0 = *(const f32x4*)&sm.g.adjS[0][kb + k];
                f32x4 a1 = *(const f32x4*)&sm.g.adjS[1][kb + k];
                f32x4 a2 = *(const f32x4*)&sm.g.adjS[2][kb + k];
                f32x4 a3 = *(const f32x4*)&sm.g.adjS[3][kb + k];
                const float* vp = vin + (size_t)(kb + k) * DD + d;
                float vk0 = vp[0], vk1 = vp[DD], vk2 = vp[2 * DD], vk3 = vp[3 * DD];
                ac0 = fmaf(a0[0], vk0, ac0); ac1 = fmaf(a1[0], vk0, ac1);
                ac2 = fmaf(a2[0], vk0, ac2); ac3 = fmaf(a3[0], vk0, ac3);
                ac0 = fmaf(a0[1], vk1, ac0); ac1 = fmaf(a1[1], vk1, ac1);
                ac2 = fmaf(a2[1], vk1, ac2); ac3 = fmaf(a3[1], vk1, ac3);
                ac0 = fmaf(a0[2], vk2, ac0); ac1 = fmaf(a1[2], vk2, ac1);
                ac2 = fmaf(a2[2], vk2, ac2); ac3 = fmaf(a3[2], vk2, ac3);
                ac0 = fmaf(a0[3], vk3, ac0); ac1 = fmaf(a1[3], vk3, ac1);
                ac2 = fmaf(a2[3], vk3, ac2); ac3 = fmaf(a3[3], vk3, ac3);
            }
            sm.g.pS[kk][0][d] = ac0; sm.g.pS[kk][1][d] = ac1;
            sm.g.pS[kk][2][d] = ac2; sm.g.pS[kk][3][d] = ac3;
        }
        __syncthreads();
        if (tid < 512) {
            int r = tid >> 7, d = tid & 127;
            float s = 0.f;
#pragma unroll
            for (int c = 0; c < 8; ++c) s += sm.g.pS[c][r][d];
            sm.g.aggS[r][d] = s;
        }
        __syncthreads();
        // gate = sigmoid(u @ WA + agg @ WB + bg)
        {
            int half = tid >> 9, r = (tid >> 7) & 3, d = tid & 127;
            const float* WA = Wg + l * (2 * DD * DD) + (half ? DD * DD : 0);
            sm.g.gacc[half][r][d] = dotW(WA, half ? sm.g.aggS[r] : uS[r], d);
        }
        __syncthreads();
        if (tid < 512) {
            int r = tid >> 7, d = tid & 127;
            float g = 1.f / (1.f + __expf(-(sm.g.gacc[0][r][d] + sm.g.gacc[1][r][d] + bg[l * DD + d])));
            float nh = fmaf(g, sm.g.aggS[r][d], hS[r][d]);
            hS[r][d] = nh > 0.f ? nh : 0.f;
        }
        __syncthreads();
        // next-layer u/v GEMM, or classifier head at l==2
        {
            int half = tid >> 9, r = (tid >> 7) & 3, d = tid & 127;
            const float* W2 = (l < 2) ? ((half ? Wv : Wu) + (l + 1) * DD * DD)
                                      : (Wc1 + (half ? DD * DD : 0));
            float av = dotW(W2, hS[r], d);
            if (l < 2) {
                if (!half) uS[r][d] = av + bu[(l + 1) * DD + d];
                else       vout[(size_t)(row0 + r) * DD + d] = av + bv[(l + 1) * DD + d];
            } else {
                float val = av + (half ? 0.f : bc1[d]);
                (half ? hj : hi)[(size_t)(row0 + r) * DD + d] = val;
                float p = val * Wc2[d];
#pragma unroll
                for (int off = 32; off; off >>= 1) p += __shfl_down(p, off);
                if ((tid & 63) == 0) sm.g.sred[half][r][(tid >> 6) & 1] = p;
            }
        }
        if (l == 2) {
            __syncthreads();
            if (tid < 4) S1[row0 + tid] = sm.g.sred[0][tid][0] + sm.g.sred[0][tid][1];
            else if (tid < 8) S2[row0 + tid - 4] = sm.g.sred[1][tid - 4][0] + sm.g.sred[1][tid - 4][1];
        }
        gridbar(barCnt, ++ep);
    }

    // ---------------- edge classifier: two 64x32 tiles per block + loss ----------------
    if (tid < 128) wS[tid] = Wc2[tid];
    float lsum = 0.f;
    float bcv = bc2[0];
    for (int t = bx; t < 512; t += NBLK) {
        int i0 = (t >> 5) << 6;       // 16 i-tiles of 64
        int j0 = (t & 31) << 5;       // 32 j-tiles of 32
        __syncthreads();
        for (int e2 = tid; e2 < 64 * 128; e2 += 1024) {
            int r = e2 >> 7, hh = e2 & 127;
            sm.e.hiS[r][hh] = hi[(size_t)(i0 + r) * DD + hh];
        }
        for (int e2 = tid; e2 < 32 * 128; e2 += 1024) {
            int r = e2 >> 7, hh = e2 & 127;
            sm.e.hjS[r][hh] = hj[(size_t)(j0 + r) * DD + hh];
        }
        __syncthreads();
        int i = tid >> 4;                  // 0..63
        int j2 = (tid & 15) << 1;          // 0,2,..,30
        float acc0 = 0.f, acc1 = 0.f;
#pragma unroll 4
        for (int hh = 0; hh < 128; hh += 4) {
            f32x4 a4 = *(const f32x4*)&sm.e.hiS[i][hh];
            f32x4 b0 = *(const f32x4*)&sm.e.hjS[j2][hh];
            f32x4 b1 = *(const f32x4*)&sm.e.hjS[j2 + 1][hh];
            f32x4 w4 = *(const f32x4*)&wS[hh];
#pragma unroll
            for (int q = 0; q < 4; ++q) {
                acc0 = fmaf(fabsf(a4[q] + b0[q]), w4[q], acc0);
                acc1 = fmaf(fabsf(a4[q] + b1[q]), w4[q], acc1);
            }
        }
        float s1 = S1[i0 + i];
        float2 s2 = *(const float2*)(S2 + j0 + j2);
        float lg0 = fmaf(0.5f, acc0 + s1 + s2.x, bcv);
        float lg1 = fmaf(0.5f, acc1 + s1 + s2.y, bcv);
        size_t off = (size_t)(i0 + i) * NN + j0 + j2;
        float2 lg; lg.x = lg0; lg.y = lg1;
        *(float2*)(outL + off) = lg;
        float2 a2 = *(const float2*)(adj + off);
        float2 e2v = *(const float2*)(ew + off);
        float t0 = fmaf(lg0, a2.x, -e2v.x);
        float t1 = fmaf(lg1, a2.y, -e2v.y);
        lsum = fmaf(t0, t0, fmaf(t1, t1, lsum));
    }
#pragma unroll
    for (int off = 32; off; off >>= 1) lsum += __shfl_down(lsum, off);
    if ((tid & 63) == 0) sm.e.lred[tid >> 6] = lsum;
    __syncthreads();
    if (tid == 0) {
        float bls = 0.f;
#pragma unroll
        for (int w = 0; w < 16; ++w) bls += sm.e.lred[w];
        atomicAdd(lossAcc, bls);
        __threadfence();
        unsigned old = atomicAdd(counter, 1u);
        if (old == NBLK - 1u) {
            __threadfence();
            outL[(size_t)NN * NN] = (*(volatile float*)lossAcc) * (1.f / (1024.f * 1024.f));
        }
    }
}

extern "C" void kernel_launch(void* const* d_in, const int* in_sizes, int n_in,
                              void* d_out, int out_size, void* d_ws, size_t ws_size,
                              hipStream_t stream)
{
    const float* nf  = (const float*)d_in[0];
    const float* adj = (const float*)d_in[1];
    const float* ew  = (const float*)d_in[2];
    const float* We  = (const float*)d_in[3];
    const float* be  = (const float*)d_in[4];
    const float* Wu  = (const float*)d_in[5];
    const float* bu  = (const float*)d_in[6];
    const float* Wv  = (const float*)d_in[7];
    const float* bv  = (const float*)d_in[8];
    const float* Wg  = (const float*)d_in[9];
    const float* bg  = (const float*)d_in[10];
    const float* Wc1 = (const float*)d_in[11];
    const float* bc1 = (const float*)d_in[12];
    const float* Wc2 = (const float*)d_in[13];
    const float* bc2 = (const float*)d_in[14];

    float* ws = (float*)d_ws;
    float* v0  = ws;                                 // 131072
    float* v1  = ws + 131072;                        // 131072
    float* hi  = ws + 262144;                        // 131072
    float* hj  = ws + 393216;                        // 131072
    float* S1  = ws + 524288;                        // 1024
    float* S2  = ws + 525312;                        // 1024
    float* lossAcc = ws + 526336;                    // 1
    unsigned* counter = (unsigned*)(ws + 526337);    // 1
    unsigned* barCnt = (unsigned*)(ws + 526368);     // 545 uints (sub/master/flag)

    // zero lossAcc + counter + barrier state (capture-legal)
    hipMemsetAsync((void*)lossAcc, 0, 2560, stream);
    k_fused<<<NBLK, 1024, 0, stream>>>(adj, ew, nf, We, be, Wu, bu, Wv, bv, Wg, bg,
                                       Wc1, bc1, Wc2, bc2, v0, v1, hi, hj, S1, S2,
                                       lossAcc, counter, barCnt, (float*)d_out);
}